// Round 12
// baseline (301.929 us; speedup 1.0000x reference)
//
#include <hip/hip_runtime.h>
#include <stdint.h>

// QuantizedLinear: out = x @ dequant(q,s)^T + bias
// Pure-i8 path (R11) + R12 memory restructure:
//  - A (x, 8MB) read DIRECTLY from global per-frag (L1/L2-resident; 4 waves
//    sharing wm hit L1). A no longer staged to LDS.
//  - B in LDS: 4 buffers x 32KB (128KB), distance-3 prefetch.
//  - Cross-step register double-buffer: step t MFMAs frags(t) (in regs),
//    reads frags(t+1) (B ds_read + A global) -> MFMA never waits same-step
//    loads. Compiler's own counted vmcnt before each A-use gates the B tile
//    two steps ahead (FIFO order: B staged before A loads each step), and the
//    per-step barrier makes it cross-wave visible. One barrier per step.
#define M_DIM 2048
#define K_DIM 4096
#define N_DIM 11008
#define KB2   (K_DIM / 2)
#define NGRP  32

#define TBM 128
#define TBN 256
#define TBK 128
#define NT  (K_DIM / TBK)     // 32 K-steps
#define BBUF 32768            // bytes per B LDS buffer (256 x 128 i8)
#define BMASK (4 * BBUF - 1)  // 131071 (4 buffers, power-of-2 rotation)

#define XRANGE 5.0f
#define XSCALE (127.0f / XRANGE)
#define XINV   (XRANGE / 127.0f)

// fallback tile (bf16 fused path, no workspace)
#define BM 128
#define BN 128
#define BK 64

typedef __attribute__((ext_vector_type(4))) int   i32x4;
typedef __attribute__((ext_vector_type(4))) float f32x4;
typedef __attribute__((ext_vector_type(8))) short bf16x8;

__device__ __forceinline__ unsigned short f2bf(float f) {
  union { float f; unsigned u; } v; v.f = f;
  return (unsigned short)((v.u + 0x7FFFu + ((v.u >> 16) & 1u)) >> 16);
}

__device__ __forceinline__ void gload_lds16(const void* g, void* l) {
  __builtin_amdgcn_global_load_lds(
      (__attribute__((address_space(1))) void*)(g),
      (__attribute__((address_space(3))) void*)(l), 16, 0, 0);
}

__device__ __forceinline__ int q127(float v) {
  float qf = fminf(127.0f, fmaxf(-127.0f, rintf(v * XSCALE)));
  return (int)qf;
}

// ---------------- prepass: x f32 -> i8 (fixed scale) ----------------
__global__ void quant_x_kernel(const float* __restrict__ x,
                               signed char* __restrict__ xq) {
  const size_t total = (size_t)M_DIM * K_DIM / 16;
  for (size_t u = (size_t)blockIdx.x * blockDim.x + threadIdx.x; u < total;
       u += (size_t)gridDim.x * blockDim.x) {
    const float4* src = (const float4*)(x + u * 16);
    int4 o;
    int* op = (int*)&o;
#pragma unroll
    for (int i = 0; i < 4; ++i) {
      float4 f = src[i];
      int q0 = q127(f.x), q1 = q127(f.y), q2 = q127(f.z), q3 = q127(f.w);
      op[i] = (q0 & 255) | ((q1 & 255) << 8) | ((q2 & 255) << 16) | ((q3 & 255) << 24);
    }
    *(int4*)(xq + u * 16) = o;
  }
}

// ---------------- prepass: per-row scale prep ----------------
__global__ void rowscale_kernel(const float* __restrict__ s,
                                float* __restrict__ d_inv,
                                float* __restrict__ rowScale) {
  int o = blockIdx.x * blockDim.x + threadIdx.x;
  if (o >= N_DIM) return;
  const float4* sp = (const float4*)(s + o * NGRP);
  float m = 0.0f;
#pragma unroll
  for (int i = 0; i < 8; ++i) {
    float4 v = sp[i];
    m = fmaxf(m, fmaxf(fmaxf(v.x, v.y), fmaxf(v.z, v.w)));
  }
  float d = 8.0f * m / 127.0f;
  d_inv[o] = 1.0f / d;
  rowScale[o] = d * XINV;
}

// ---------------- prepass: packed int4 -> requantized i8 W [N, K] ----------------
__global__ void unpack_w_kernel(const int* __restrict__ q,
                                const float* __restrict__ s,
                                const float* __restrict__ d_inv,
                                signed char* __restrict__ W) {
  const size_t total = (size_t)N_DIM * KB2 / 8;
  for (size_t u = (size_t)blockIdx.x * blockDim.x + threadIdx.x; u < total;
       u += (size_t)gridDim.x * blockDim.x) {
    size_t qi = u * 8;
    unsigned o = (unsigned)(qi >> 11);
    unsigned c = (unsigned)(qi & 2047);
    float sc = s[o * NGRP + (c >> 6)] * d_inv[o];
    int4 v0 = *(const int4*)(q + qi);
    int4 v1 = *(const int4*)(q + qi + 4);
    int4 out;
    int* op = (int*)&out;
#pragma unroll
    for (int i = 0; i < 2; ++i) {
      const int* vv = i ? (const int*)&v1 : (const int*)&v0;
#pragma unroll
      for (int p = 0; p < 2; ++p) {
        int a = vv[p * 2], b = vv[p * 2 + 1];
        int q0 = (int)rintf((float)((a & 15) - 8) * sc);
        int q1 = (int)rintf((float)(((a >> 4) & 15) - 8) * sc);
        int q2 = (int)rintf((float)((b & 15) - 8) * sc);
        int q3 = (int)rintf((float)(((b >> 4) & 15) - 8) * sc);
        op[i * 2 + p] = (q0 & 255) | ((q1 & 255) << 8) | ((q2 & 255) << 16) | ((q3 & 255) << 24);
      }
    }
    *(int4*)(W + qi * 2) = out;
  }
}

// ---------------- main GEMM: C = Xq * Wq^T (i8), epilogue row scale + bias ----------------
__global__ __launch_bounds__(512, 2) void gemm_i8_kernel(
    const signed char* __restrict__ A, const signed char* __restrict__ B,
    const float* __restrict__ rowScale, const float* __restrict__ bias,
    float* __restrict__ C) {
  __shared__ signed char lds[4 * BBUF];  // 128 KB, B tiles only

  const int tid = threadIdx.x;
  const int w = tid >> 6, lane = tid & 63;

  // T1: XCD-chunked bijective swizzle (688 = 8 * 86), m-fast within XCD.
  const int hw = blockIdx.x;
  const int wg = (hw & 7) * 86 + (hw >> 3);
  const int m0 = (wg % 16) * TBM;
  const int n0 = (wg / 16) * TBN;

  const int lane16 = lane & 15, lq = lane >> 4;
  const int wm = (w >> 2) * 64, wn = (w & 3) * 64;

  // ---- B staging: 4 issues/tile, 512 thr x 16B = 64 rows each.
  // Inverse swizzle on global k: slot s of row r holds k-chunk s ^ (r&7).
  const int kx = (((tid & 7) ^ ((tid >> 3) & 7)) << 4);  // bytes
  const signed char* Bg = B + (size_t)(n0 + (tid >> 3)) * K_DIM + kx;
  const int wBase = w * 1024;  // wave-uniform LDS staging base (bytes)

#define STAGE(bufo, t2) {                                                      \
    const signed char* b_ = Bg + (size_t)(t2) * TBK;                           \
    gload_lds16(b_,                       lds + (bufo) + wBase);               \
    gload_lds16(b_ + (size_t)64 * K_DIM,  lds + (bufo) + 8192 + wBase);        \
    gload_lds16(b_ + (size_t)128 * K_DIM, lds + (bufo) + 16384 + wBase);       \
    gload_lds16(b_ + (size_t)192 * K_DIM, lds + (bufo) + 24576 + wBase);       \
  }

  // ---- B ds_read (swizzled): byte = row*128 + ((kk*4+lq) ^ (row&7))*16
  int bOff[4][2];
#pragma unroll
  for (int j = 0; j < 4; ++j)
#pragma unroll
    for (int kk = 0; kk < 2; ++kk)
      bOff[j][kk] = (wn + j * 16 + lane16) * 128 + (((kk * 4 + lq) ^ (lane16 & 7)) << 4);

  // ---- A direct-from-global frag base: lane reads row (m0+wm+i*16+lane16),
  // bytes t*128 + kk*64 + lq*16. Each load = 16 rows x one 64B line (clean).
  const signed char* Aw = A + (size_t)(m0 + wm + lane16) * K_DIM + lq * 16;

#define LOADA(dst, t2) {                                                       \
    _Pragma("unroll")                                                          \
    for (int i = 0; i < 4; ++i)                                                \
      _Pragma("unroll")                                                        \
      for (int kk = 0; kk < 2; ++kk)                                           \
        dst[i][kk] = *(const i32x4*)(Aw + (size_t)i * 16 * K_DIM +             \
                                     (size_t)(t2) * TBK + kk * 64); }
#define READB(dst, bufo) {                                                     \
    _Pragma("unroll")                                                          \
    for (int j = 0; j < 4; ++j)                                                \
      _Pragma("unroll")                                                        \
      for (int kk = 0; kk < 2; ++kk)                                           \
        dst[j][kk] = *(const i32x4*)(lds + (bufo) + bOff[j][kk]); }
#define MFMA16(AV, BV) {                                                       \
    __builtin_amdgcn_s_setprio(1);                                             \
    _Pragma("unroll")                                                          \
    for (int u = 0; u < 16; ++u) {                                             \
      const int pi = u & 3, pj = u >> 2;                                       \
      i32x4 tmp_ = __builtin_amdgcn_mfma_i32_16x16x64_i8(AV[pi][0], BV[pj][0], \
                                                         iacc[pi][pj], 0, 0, 0);\
      iacc[pi][pj] = __builtin_amdgcn_mfma_i32_16x16x64_i8(AV[pi][1], BV[pj][1],\
                                                           tmp_, 0, 0, 0);     \
    }                                                                          \
    __builtin_amdgcn_s_setprio(0); }

  i32x4 iacc[4][4];
#pragma unroll
  for (int i = 0; i < 4; ++i)
#pragma unroll
    for (int j = 0; j < 4; ++j) iacc[i][j] = (i32x4){0, 0, 0, 0};

  i32x4 avA[4][2], bvA[4][2], avB[4][2], bvB[4][2];

  // prologue: stage B tiles 0,1,2 (12 DMA); load A(0); drain; read B-frags(0)
  STAGE(0 * BBUF, 0);
  STAGE(1 * BBUF, 1);
  STAGE(2 * BBUF, 2);
  LOADA(avA, 0);
  asm volatile("s_waitcnt vmcnt(0)" ::: "memory");
  __builtin_amdgcn_s_barrier();
  READB(bvA, 0);

  int rdBuf = BBUF, stBuf = 3 * BBUF;
  // steady state per step t: {stage B(t+3); load A(t+1); read B-frags(t+1);
  //  MFMA frags(t); barrier}. Unroll x2 for static reg double-buffer.
  for (int t = 0; t < NT; t += 2) {
    // even half: consume (avA,bvA)=frags(t), fill (avB,bvB)=frags(t+1)
    if (t + 3 < NT) STAGE(stBuf, t + 3);
    if (t + 1 < NT) {
      LOADA(avB, t + 1);
      READB(bvB, rdBuf);
    }
    MFMA16(avA, bvA);
    __builtin_amdgcn_s_barrier();
    rdBuf = (rdBuf + BBUF) & BMASK;
    stBuf = (stBuf + BBUF) & BMASK;

    // odd half: consume (avB,bvB)=frags(t+1), fill (avA,bvA)=frags(t+2)
    if (t + 4 < NT) STAGE(stBuf, t + 4);
    if (t + 2 < NT) {
      LOADA(avA, t + 2);
      READB(bvA, rdBuf);
    }
    MFMA16(avB, bvB);
    __builtin_amdgcn_s_barrier();
    rdBuf = (rdBuf + BBUF) & BMASK;
    stBuf = (stBuf + BBUF) & BMASK;
  }
#undef STAGE
#undef LOADA
#undef READB
#undef MFMA16

  // epilogue: D mapping col=lane&15, row=(lane>>4)*4+r
  const int row0 = m0 + wm + (lane >> 4) * 4;
  const int col0 = n0 + wn + lane16;
#pragma unroll
  for (int j = 0; j < 4; ++j) {
    const int col = col0 + j * 16;
    float rs = rowScale[col];
    float bvs = bias[col];
#pragma unroll
    for (int i = 0; i < 4; ++i) {
#pragma unroll
      for (int r = 0; r < 4; ++r) {
        C[(size_t)(row0 + i * 16 + r) * N_DIM + col] =
            (float)iacc[i][j][r] * rs + bvs;
      }
    }
  }
}

// ---------------- fallback: fused bf16 dequant GEMM (no workspace needed) ----------------
__global__ __launch_bounds__(256, 2) void gemm_fused_kernel(
    const float* __restrict__ x, const int* __restrict__ q,
    const float* __restrict__ s, const float* __restrict__ bias,
    float* __restrict__ C) {
  __shared__ unsigned short As[BM * BK];
  __shared__ unsigned short Bs[BN * BK];

  const int tid = threadIdx.x;
  const int wave = tid >> 6, lane = tid & 63;
  const int m0 = blockIdx.y * BM, n0 = blockIdx.x * BN;
  const int wm = (wave >> 1) * 64, wn = (wave & 1) * 64;

  f32x4 acc[4][4] = {};

  const int r2 = tid >> 1;
  const int kh = (tid & 1) * 32;
  const float* xg = x + (size_t)(m0 + r2) * K_DIM + kh;
  const int* qg = q + (size_t)(n0 + r2) * KB2 + (tid & 1) * 16;
  const float* sg = s + (size_t)(n0 + r2) * NGRP;
  unsigned short* Asp = &As[r2 * BK + kh];
  unsigned short* Bsp = &Bs[r2 * BK + kh];

  const int lane16 = lane & 15;
  const int kq = (lane >> 4) * 8;

  for (int t = 0; t < K_DIM / BK; ++t) {
    union { unsigned short h[8]; bf16x8 v; } oA[4], oB[4];
#pragma unroll
    for (int j = 0; j < 4; ++j) {
      float4 f0 = *(const float4*)(xg + t * BK + j * 8);
      float4 f1 = *(const float4*)(xg + t * BK + j * 8 + 4);
      oA[j].h[0] = f2bf(f0.x); oA[j].h[1] = f2bf(f0.y); oA[j].h[2] = f2bf(f0.z); oA[j].h[3] = f2bf(f0.w);
      oA[j].h[4] = f2bf(f1.x); oA[j].h[5] = f2bf(f1.y); oA[j].h[6] = f2bf(f1.z); oA[j].h[7] = f2bf(f1.w);
    }
    float sc = sg[t >> 1];
#pragma unroll
    for (int j = 0; j < 4; ++j) {
      int4 qv = *(const int4*)(qg + t * 32 + j * 4);
      int b;
      b = qv.x; oB[j].h[0] = f2bf((float)((b & 15) - 8) * sc); oB[j].h[1] = f2bf((float)(((b >> 4) & 15) - 8) * sc);
      b = qv.y; oB[j].h[2] = f2bf((float)((b & 15) - 8) * sc); oB[j].h[3] = f2bf((float)(((b >> 4) & 15) - 8) * sc);
      b = qv.z; oB[j].h[4] = f2bf((float)((b & 15) - 8) * sc); oB[j].h[5] = f2bf((float)(((b >> 4) & 15) - 8) * sc);
      b = qv.w; oB[j].h[6] = f2bf((float)((b & 15) - 8) * sc); oB[j].h[7] = f2bf((float)(((b >> 4) & 15) - 8) * sc);
    }
    __syncthreads();
#pragma unroll
    for (int j = 0; j < 4; ++j) {
      *(bf16x8*)(Asp + j * 8) = oA[j].v;
      *(bf16x8*)(Bsp + j * 8) = oB[j].v;
    }
    __syncthreads();
#pragma unroll
    for (int kk = 0; kk < 2; ++kk) {
      const int ko = kk * 32 + kq;
      bf16x8 av[4], bv[4];
#pragma unroll
      for (int i = 0; i < 4; ++i)
        av[i] = *(const bf16x8*)&As[(wm + i * 16 + lane16) * BK + ko];
#pragma unroll
      for (int i = 0; i < 4; ++i)
        bv[i] = *(const bf16x8*)&Bs[(wn + i * 16 + lane16) * BK + ko];
#pragma unroll
      for (int i = 0; i < 4; ++i)
#pragma unroll
        for (int j = 0; j < 4; ++j)
          acc[i][j] = __builtin_amdgcn_mfma_f32_16x16x32_bf16(av[i], bv[j], acc[i][j], 0, 0, 0);
    }
  }

  const int col0 = n0 + wn + lane16;
  const int row0 = m0 + wm + (lane >> 4) * 4;
#pragma unroll
  for (int j = 0; j < 4; ++j) {
    float bvs = bias[col0 + j * 16];
#pragma unroll
    for (int i = 0; i < 4; ++i) {
#pragma unroll
      for (int r = 0; r < 4; ++r) {
        C[(size_t)(row0 + i * 16 + r) * N_DIM + (col0 + j * 16)] = acc[i][j][r] + bvs;
      }
    }
  }
}

extern "C" void kernel_launch(void* const* d_in, const int* in_sizes, int n_in,
                              void* d_out, int out_size, void* d_ws, size_t ws_size,
                              hipStream_t stream) {
  const float* x = (const float*)d_in[0];
  const int* q = (const int*)d_in[1];
  const float* s = (const float*)d_in[2];
  const float* b = (const float*)d_in[3];
  float* out = (float*)d_out;

  const size_t w_bytes = (size_t)N_DIM * K_DIM;          // 45,088,768 (i8 W)
  const size_t x_bytes = (size_t)M_DIM * K_DIM;          // 8,388,608  (i8 x)
  const size_t r_bytes = (size_t)N_DIM * 4;              // 44,032 each
  const size_t need = w_bytes + x_bytes + 2 * r_bytes;   // ~54 MB

  if (ws_size >= need) {
    signed char* Wq = (signed char*)d_ws;
    signed char* Xq = Wq + w_bytes;
    float* d_inv = (float*)(Wq + w_bytes + x_bytes);
    float* rowScale = d_inv + N_DIM;
    quant_x_kernel<<<dim3(2048), dim3(256), 0, stream>>>(x, Xq);
    rowscale_kernel<<<dim3((N_DIM + 255) / 256), dim3(256), 0, stream>>>(s, d_inv, rowScale);
    unpack_w_kernel<<<dim3(2048), dim3(256), 0, stream>>>(q, s, d_inv, Wq);
    gemm_i8_kernel<<<dim3((N_DIM / TBN) * (M_DIM / TBM)), dim3(512), 0, stream>>>(Xq, Wq, rowScale, b, out);
  } else {
    gemm_fused_kernel<<<dim3(N_DIM / BN, M_DIM / BM), dim3(256), 0, stream>>>(x, q, s, b, out);
  }
}

// Round 13
// 189.741 us; speedup vs baseline: 1.5913x; 1.5913x over previous
//
#include <hip/hip_runtime.h>
#include <stdint.h>

// QuantizedLinear: out = x @ dequant(q,s)^T + bias
// Pure-i8 path (R11 numerics) + R13 memory restructure:
//  - A (xq) stored FRAGMENT-ORDERED by the quant prepass: frag(rt=m/16, c=k/64)
//    = contiguous 1KB, lane slot (m&15)*4+(k%64)/16. GEMM reads A via fully
//    coalesced 1KB global_load_dwordx4 (L1/L2-resident, 4 waves share wm).
//    A is NOT staged to LDS (removes 16KB/step DMA + 64KB/step LDS reads).
//  - B in LDS exactly as R11: 3 x 32KB buffers, distance-2 prefetch,
//    both-sides swizzle (slot ^ row&7), counted vmcnt.
//  - Cross-step A register double-buffer (named sets avA/avB, static indexing).
#define M_DIM 2048
#define K_DIM 4096
#define N_DIM 11008
#define KB2   (K_DIM / 2)
#define NGRP  32

#define TBM 128
#define TBN 256
#define TBK 128
#define NT  (K_DIM / TBK)     // 32 K-steps
#define BBUF 32768            // bytes per B LDS buffer (256 x 128 i8)

#define XRANGE 5.0f
#define XSCALE (127.0f / XRANGE)
#define XINV   (XRANGE / 127.0f)

// fallback tile (bf16 fused path, no workspace)
#define BM 128
#define BN 128
#define BK 64

typedef __attribute__((ext_vector_type(4))) int   i32x4;
typedef __attribute__((ext_vector_type(4))) float f32x4;
typedef __attribute__((ext_vector_type(8))) short bf16x8;

__device__ __forceinline__ unsigned short f2bf(float f) {
  union { float f; unsigned u; } v; v.f = f;
  return (unsigned short)((v.u + 0x7FFFu + ((v.u >> 16) & 1u)) >> 16);
}

__device__ __forceinline__ void gload_lds16(const void* g, void* l) {
  __builtin_amdgcn_global_load_lds(
      (__attribute__((address_space(1))) void*)(g),
      (__attribute__((address_space(3))) void*)(l), 16, 0, 0);
}

__device__ __forceinline__ int q127(float v) {
  float qf = fminf(127.0f, fmaxf(-127.0f, rintf(v * XSCALE)));
  return (int)qf;
}

// ---------------- prepass: x f32 -> i8, FRAGMENT-ORDERED ----------------
// thread u: row m = u>>8, 16-k chunk k16 = u&255. Output byte address:
// ((m>>4)*64 + (k16>>2))*1024 + ((m&15)*4 + (k16&3))*16
__global__ void quant_x_kernel(const float* __restrict__ x,
                               signed char* __restrict__ xf) {
  const size_t total = (size_t)M_DIM * K_DIM / 16;
  for (size_t u = (size_t)blockIdx.x * blockDim.x + threadIdx.x; u < total;
       u += (size_t)gridDim.x * blockDim.x) {
    int m = (int)(u >> 8);
    int k16 = (int)(u & 255);
    const float4* src = (const float4*)(x + (size_t)m * K_DIM + k16 * 16);
    int4 o;
    int* op = (int*)&o;
#pragma unroll
    for (int i = 0; i < 4; ++i) {
      float4 f = src[i];
      int q0 = q127(f.x), q1 = q127(f.y), q2 = q127(f.z), q3 = q127(f.w);
      op[i] = (q0 & 255) | ((q1 & 255) << 8) | ((q2 & 255) << 16) | ((q3 & 255) << 24);
    }
    size_t off = (((size_t)(m >> 4) * 64 + (k16 >> 2)) << 10) +
                 (size_t)(((m & 15) * 4 + (k16 & 3)) * 16);
    *(int4*)(xf + off) = o;
  }
}

// ---------------- prepass: per-row scale prep ----------------
__global__ void rowscale_kernel(const float* __restrict__ s,
                                float* __restrict__ d_inv,
                                float* __restrict__ rowScale) {
  int o = blockIdx.x * blockDim.x + threadIdx.x;
  if (o >= N_DIM) return;
  const float4* sp = (const float4*)(s + o * NGRP);
  float m = 0.0f;
#pragma unroll
  for (int i = 0; i < 8; ++i) {
    float4 v = sp[i];
    m = fmaxf(m, fmaxf(fmaxf(v.x, v.y), fmaxf(v.z, v.w)));
  }
  float d = 8.0f * m / 127.0f;
  d_inv[o] = 1.0f / d;
  rowScale[o] = d * XINV;
}

// ---------------- prepass: packed int4 -> requantized i8 W [N, K] ----------------
__global__ void unpack_w_kernel(const int* __restrict__ q,
                                const float* __restrict__ s,
                                const float* __restrict__ d_inv,
                                signed char* __restrict__ W) {
  const size_t total = (size_t)N_DIM * KB2 / 8;
  for (size_t u = (size_t)blockIdx.x * blockDim.x + threadIdx.x; u < total;
       u += (size_t)gridDim.x * blockDim.x) {
    size_t qi = u * 8;
    unsigned o = (unsigned)(qi >> 11);
    unsigned c = (unsigned)(qi & 2047);
    float sc = s[o * NGRP + (c >> 6)] * d_inv[o];
    int4 v0 = *(const int4*)(q + qi);
    int4 v1 = *(const int4*)(q + qi + 4);
    int4 out;
    int* op = (int*)&out;
#pragma unroll
    for (int i = 0; i < 2; ++i) {
      const int* vv = i ? (const int*)&v1 : (const int*)&v0;
#pragma unroll
      for (int p = 0; p < 2; ++p) {
        int a = vv[p * 2], b = vv[p * 2 + 1];
        int q0 = (int)rintf((float)((a & 15) - 8) * sc);
        int q1 = (int)rintf((float)(((a >> 4) & 15) - 8) * sc);
        int q2 = (int)rintf((float)((b & 15) - 8) * sc);
        int q3 = (int)rintf((float)(((b >> 4) & 15) - 8) * sc);
        op[i * 2 + p] = (q0 & 255) | ((q1 & 255) << 8) | ((q2 & 255) << 16) | ((q3 & 255) << 24);
      }
    }
    *(int4*)(W + qi * 2) = out;
  }
}

// ---------------- main GEMM: C = Xq * Wq^T (i8), epilogue row scale + bias ----------------
__global__ __launch_bounds__(512, 2) void gemm_i8_kernel(
    const signed char* __restrict__ Af, const signed char* __restrict__ B,
    const float* __restrict__ rowScale, const float* __restrict__ bias,
    float* __restrict__ C) {
  __shared__ signed char lds[3 * BBUF];  // 96 KB, B only

  const int tid = threadIdx.x;
  const int w = tid >> 6, lane = tid & 63;

  // T1: XCD-chunked bijective swizzle (688 = 8 * 86), m-fast within XCD.
  const int hw = blockIdx.x;
  const int wg = (hw & 7) * 86 + (hw >> 3);
  const int m0 = (wg % 16) * TBM;
  const int n0 = (wg / 16) * TBN;

  const int lane16 = lane & 15, lq = lane >> 4;
  const int wm = (w >> 2) * 64, wn = (w & 3) * 64;

  // ---- B staging (as R11): 4 issues/tile, row tid>>3, slot tid&7,
  // inverse swizzle on global k: slot s of row r holds k-chunk s ^ (r&7).
  const int kx = (((tid & 7) ^ ((tid >> 3) & 7)) << 4);
  const signed char* Bg = B + (size_t)(n0 + (tid >> 3)) * K_DIM + kx;
  const int wBase = w * 1024;

#define STAGE(bufo, t2) {                                                      \
    const signed char* b_ = Bg + (size_t)(t2) * TBK;                           \
    gload_lds16(b_,                       lds + (bufo) + wBase);               \
    gload_lds16(b_ + (size_t)64 * K_DIM,  lds + (bufo) + 8192 + wBase);        \
    gload_lds16(b_ + (size_t)128 * K_DIM, lds + (bufo) + 16384 + wBase);       \
    gload_lds16(b_ + (size_t)192 * K_DIM, lds + (bufo) + 24576 + wBase);       \
  }

  // ---- B ds_read (swizzled): byte = row*128 + ((kk*4+lq) ^ (row&7))*16
  int bOff[4][2];
#pragma unroll
  for (int j = 0; j < 4; ++j)
#pragma unroll
    for (int kk = 0; kk < 2; ++kk)
      bOff[j][kk] = (wn + j * 16 + lane16) * 128 + (((kk * 4 + lq) ^ (lane16 & 7)) << 4);

  // ---- A fragment-ordered global reads: frag(rt, c) at ((rt*64+c)<<10),
  // lane slot (lane16*4+lq)*16. Fully coalesced 1KB per load.
  const int rtB = (m0 + wm) >> 4;
  const signed char* Aw = Af + ((size_t)rtB << 16) + (size_t)((lane16 * 4 + lq) * 16);

#define LOADA(dst, t2) {                                                       \
    _Pragma("unroll")                                                          \
    for (int i = 0; i < 4; ++i)                                                \
      _Pragma("unroll")                                                        \
      for (int kk = 0; kk < 2; ++kk)                                           \
        dst[i][kk] = *(const i32x4*)(Aw + (((size_t)i * 64 + 2 * (t2) + kk) << 10)); }
#define READB(dst, bufo) {                                                     \
    _Pragma("unroll")                                                          \
    for (int j = 0; j < 4; ++j)                                                \
      _Pragma("unroll")                                                        \
      for (int kk = 0; kk < 2; ++kk)                                           \
        dst[j][kk] = *(const i32x4*)(lds + (bufo) + bOff[j][kk]); }
#define MFMA16(AV, BV) {                                                       \
    __builtin_amdgcn_s_setprio(1);                                             \
    _Pragma("unroll")                                                          \
    for (int u = 0; u < 16; ++u) {                                             \
      const int pi = u & 3, pj = u >> 2;                                       \
      i32x4 tmp_ = __builtin_amdgcn_mfma_i32_16x16x64_i8(AV[pi][0], BV[pj][0], \
                                                         iacc[pi][pj], 0, 0, 0);\
      iacc[pi][pj] = __builtin_amdgcn_mfma_i32_16x16x64_i8(AV[pi][1], BV[pj][1],\
                                                           tmp_, 0, 0, 0);     \
    }                                                                          \
    __builtin_amdgcn_s_setprio(0); }

  i32x4 iacc[4][4];
#pragma unroll
  for (int i = 0; i < 4; ++i)
#pragma unroll
    for (int j = 0; j < 4; ++j) iacc[i][j] = (i32x4){0, 0, 0, 0};

  i32x4 avA[4][2], avB[4][2], bv[4][2];

  // prologue: stage B(0),B(1); load A(0); wait B(0)+A(0) (B(1)'s 4 in flight)
  STAGE(0, 0);
  STAGE(BBUF, 1);
  LOADA(avA, 0);
  asm volatile("s_waitcnt vmcnt(4)" ::: "memory");
  __builtin_amdgcn_s_barrier();

  int cur = 0, stg = 2 * BBUF;
  // steady step t: {stage B(t+2); load A(t+1)->other reg set; read B(t);
  //  MFMA frags(t); vmcnt(12)+barrier}. Unroll x2 for static A reg dbuf.
  for (int t = 0; t < NT; t += 2) {
    // even half: consume avA = A(t)
    if (t + 2 < NT) STAGE(stg, t + 2);
    LOADA(avB, t + 1);            // t+1 <= NT-1 always (t even < NT)
    READB(bv, cur);
    MFMA16(avA, bv);
    if (t >= NT - 2) {
      asm volatile("s_waitcnt vmcnt(0)" ::: "memory");
    } else {
      asm volatile("s_waitcnt vmcnt(12)" ::: "memory");
    }
    __builtin_amdgcn_s_barrier();
    cur = (cur == 2 * BBUF) ? 0 : cur + BBUF;
    stg = (stg == 2 * BBUF) ? 0 : stg + BBUF;

    // odd half: consume avB = A(t+1)
    if (t + 3 < NT) STAGE(stg, t + 3);
    if (t + 2 < NT) LOADA(avA, t + 2);
    READB(bv, cur);
    MFMA16(avB, bv);
    if (t + 1 == NT - 1) break;
    if (t + 1 >= NT - 2) {
      asm volatile("s_waitcnt vmcnt(0)" ::: "memory");
    } else {
      asm volatile("s_waitcnt vmcnt(12)" ::: "memory");
    }
    __builtin_amdgcn_s_barrier();
    cur = (cur == 2 * BBUF) ? 0 : cur + BBUF;
    stg = (stg == 2 * BBUF) ? 0 : stg + BBUF;
  }
#undef STAGE
#undef LOADA
#undef READB
#undef MFMA16

  // epilogue: D mapping col=lane&15, row=(lane>>4)*4+r
  const int row0 = m0 + wm + (lane >> 4) * 4;
  const int col0 = n0 + wn + lane16;
#pragma unroll
  for (int j = 0; j < 4; ++j) {
    const int col = col0 + j * 16;
    float rs = rowScale[col];
    float bvs = bias[col];
#pragma unroll
    for (int i = 0; i < 4; ++i) {
#pragma unroll
      for (int r = 0; r < 4; ++r) {
        C[(size_t)(row0 + i * 16 + r) * N_DIM + col] =
            (float)iacc[i][j][r] * rs + bvs;
      }
    }
  }
}

// ---------------- fallback: fused bf16 dequant GEMM (no workspace needed) ----------------
__global__ __launch_bounds__(256, 2) void gemm_fused_kernel(
    const float* __restrict__ x, const int* __restrict__ q,
    const float* __restrict__ s, const float* __restrict__ bias,
    float* __restrict__ C) {
  __shared__ unsigned short As[BM * BK];
  __shared__ unsigned short Bs[BN * BK];

  const int tid = threadIdx.x;
  const int wave = tid >> 6, lane = tid & 63;
  const int m0 = blockIdx.y * BM, n0 = blockIdx.x * BN;
  const int wm = (wave >> 1) * 64, wn = (wave & 1) * 64;

  f32x4 acc[4][4] = {};

  const int r2 = tid >> 1;
  const int kh = (tid & 1) * 32;
  const float* xg = x + (size_t)(m0 + r2) * K_DIM + kh;
  const int* qg = q + (size_t)(n0 + r2) * KB2 + (tid & 1) * 16;
  const float* sg = s + (size_t)(n0 + r2) * NGRP;
  unsigned short* Asp = &As[r2 * BK + kh];
  unsigned short* Bsp = &Bs[r2 * BK + kh];

  const int lane16 = lane & 15;
  const int kq = (lane >> 4) * 8;

  for (int t = 0; t < K_DIM / BK; ++t) {
    union { unsigned short h[8]; bf16x8 v; } oA[4], oB[4];
#pragma unroll
    for (int j = 0; j < 4; ++j) {
      float4 f0 = *(const float4*)(xg + t * BK + j * 8);
      float4 f1 = *(const float4*)(xg + t * BK + j * 8 + 4);
      oA[j].h[0] = f2bf(f0.x); oA[j].h[1] = f2bf(f0.y); oA[j].h[2] = f2bf(f0.z); oA[j].h[3] = f2bf(f0.w);
      oA[j].h[4] = f2bf(f1.x); oA[j].h[5] = f2bf(f1.y); oA[j].h[6] = f2bf(f1.z); oA[j].h[7] = f2bf(f1.w);
    }
    float sc = sg[t >> 1];
#pragma unroll
    for (int j = 0; j < 4; ++j) {
      int4 qv = *(const int4*)(qg + t * 32 + j * 4);
      int b;
      b = qv.x; oB[j].h[0] = f2bf((float)((b & 15) - 8) * sc); oB[j].h[1] = f2bf((float)(((b >> 4) & 15) - 8) * sc);
      b = qv.y; oB[j].h[2] = f2bf((float)((b & 15) - 8) * sc); oB[j].h[3] = f2bf((float)(((b >> 4) & 15) - 8) * sc);
      b = qv.z; oB[j].h[4] = f2bf((float)((b & 15) - 8) * sc); oB[j].h[5] = f2bf((float)(((b >> 4) & 15) - 8) * sc);
      b = qv.w; oB[j].h[6] = f2bf((float)((b & 15) - 8) * sc); oB[j].h[7] = f2bf((float)(((b >> 4) & 15) - 8) * sc);
    }
    __syncthreads();
#pragma unroll
    for (int j = 0; j < 4; ++j) {
      *(bf16x8*)(Asp + j * 8) = oA[j].v;
      *(bf16x8*)(Bsp + j * 8) = oB[j].v;
    }
    __syncthreads();
#pragma unroll
    for (int kk = 0; kk < 2; ++kk) {
      const int ko = kk * 32 + kq;
      bf16x8 av[4], bv[4];
#pragma unroll
      for (int i = 0; i < 4; ++i)
        av[i] = *(const bf16x8*)&As[(wm + i * 16 + lane16) * BK + ko];
#pragma unroll
      for (int i = 0; i < 4; ++i)
        bv[i] = *(const bf16x8*)&Bs[(wn + i * 16 + lane16) * BK + ko];
#pragma unroll
      for (int i = 0; i < 4; ++i)
#pragma unroll
        for (int j = 0; j < 4; ++j)
          acc[i][j] = __builtin_amdgcn_mfma_f32_16x16x32_bf16(av[i], bv[j], acc[i][j], 0, 0, 0);
    }
  }

  const int col0 = n0 + wn + lane16;
  const int row0 = m0 + wm + (lane >> 4) * 4;
#pragma unroll
  for (int j = 0; j < 4; ++j) {
    float bvs = bias[col0 + j * 16];
#pragma unroll
    for (int i = 0; i < 4; ++i) {
#pragma unroll
      for (int r = 0; r < 4; ++r) {
        C[(size_t)(row0 + i * 16 + r) * N_DIM + (col0 + j * 16)] = acc[i][j][r] + bvs;
      }
    }
  }
}

extern "C" void kernel_launch(void* const* d_in, const int* in_sizes, int n_in,
                              void* d_out, int out_size, void* d_ws, size_t ws_size,
                              hipStream_t stream) {
  const float* x = (const float*)d_in[0];
  const int* q = (const int*)d_in[1];
  const float* s = (const float*)d_in[2];
  const float* b = (const float*)d_in[3];
  float* out = (float*)d_out;

  const size_t w_bytes = (size_t)N_DIM * K_DIM;          // 45,088,768 (i8 W)
  const size_t x_bytes = (size_t)M_DIM * K_DIM;          // 8,388,608  (i8 x, frag-ordered)
  const size_t r_bytes = (size_t)N_DIM * 4;              // 44,032 each
  const size_t need = w_bytes + x_bytes + 2 * r_bytes;   // ~54 MB

  if (ws_size >= need) {
    signed char* Wq = (signed char*)d_ws;
    signed char* Xf = Wq + w_bytes;
    float* d_inv = (float*)(Wq + w_bytes + x_bytes);
    float* rowScale = d_inv + N_DIM;
    quant_x_kernel<<<dim3(2048), dim3(256), 0, stream>>>(x, Xf);
    rowscale_kernel<<<dim3((N_DIM + 255) / 256), dim3(256), 0, stream>>>(s, d_inv, rowScale);
    unpack_w_kernel<<<dim3(2048), dim3(256), 0, stream>>>(q, s, d_inv, Wq);
    gemm_i8_kernel<<<dim3((N_DIM / TBN) * (M_DIM / TBM)), dim3(512), 0, stream>>>(Xf, Wq, rowScale, b, out);
  } else {
    gemm_fused_kernel<<<dim3(N_DIM / BN, M_DIM / BM), dim3(256), 0, stream>>>(x, q, s, b, out);
  }
}